// Round 5
// baseline (528.618 us; speedup 1.0000x reference)
//
#include <hip/hip_runtime.h>

// PowerSpectrum: out[s,n, l*f^2 + i*f + j] = (2l+1)^{-1/2} * sum_m c_l[s,n,m,i]*c_l[s,n,m,j]
// f = 128, m-count = 2l+1 (1,3,5,7), S*N = 2000.
//
// Accounting (R0-R3): timed window = 2.097 GB harness poison fill (~335 us, fixed)
// + our kernel (~190 us for 540 MB = 2.8 TB/s). Fill proves 6.25 TB/s write BW on
// this buffer. R3 (merge + NT stores) was NEUTRAL -> launch overhead refuted.
// R4 hypothesis H1: store->acc register reuse forces per-iteration vmcnt waits
// (a VGPR sourcing an in-flight store can't be redefined); with shallow register
// rotation each wave has too few stores in flight and settles at ~45% of BW.
// Fix: per section, compute ALL 16 acc[k] into distinct registers (static
// indexing, 64 VGPR), then burst 16 independent stores with no reg reuse.
// R5: identical kernel — R4 bench was an infra failure (container died twice).
// Prediction: kernel ~190 -> ~100-115 us, total 528 -> ~435-455 us.

#define NFEAT 128

typedef float v4f __attribute__((ext_vector_type(4)));

__device__ __constant__ float kCg[4] = {
    1.0f,
    0.57735026918962576451f,   // 1/sqrt(3)
    0.44721359549995793928f,   // 1/sqrt(5)
    0.37796447300922722721f};  // 1/sqrt(7)

// One l-section: scl points at the NM x 128 staged tile, ob at out + l*128*128.
// Same per-output fma order (ascending m, then *cg) as the verified absmax-0.0 kernel.
template <int NM>
__device__ __forceinline__ void do_l(const float* __restrict__ scl, float cg,
                                     float* __restrict__ ob, int i0, int j4) {
  // B fragment: c[m][4*j4 .. 4*j4+3] in registers (max 7 float4 = 28 VGPRs)
  float4 b[NM];
#pragma unroll
  for (int m = 0; m < NM; ++m) b[m] = ((const float4*)scl)[m * 32 + j4];

  // Phase 1: compute all 16 row-results into DISTINCT registers (64 VGPRs).
  // 16 independent fma chains -> plenty of ILP to hide LDS broadcast latency.
  float4 acc[16];
#pragma unroll
  for (int k = 0; k < 16; ++k) {
    const int i = i0 + 8 * k;
    float4 a4 = {0.f, 0.f, 0.f, 0.f};
#pragma unroll
    for (int m = 0; m < NM; ++m) {
      const float a = scl[m * NFEAT + i];  // 2-address wave-broadcast LDS read
      a4.x += a * b[m].x;
      a4.y += a * b[m].y;
      a4.z += a * b[m].z;
      a4.w += a * b[m].w;
    }
    a4.x *= cg; a4.y *= cg; a4.z *= cg; a4.w *= cg;
    acc[k] = a4;
  }

  // Phase 2: burst 16 independent non-temporal stores, no source-register reuse
  // -> no vmcnt stalls between stores, 16 KB in flight per wave.
#pragma unroll
  for (int k = 0; k < 16; ++k) {
    const int i = i0 + 8 * k;
    v4f v = {acc[k].x, acc[k].y, acc[k].z, acc[k].w};
    __builtin_nontemporal_store(v, (v4f*)(ob + i * NFEAT) + j4);
  }
}

__global__ __launch_bounds__(256) void ps_all(const float* __restrict__ c0,
                                              const float* __restrict__ c1,
                                              const float* __restrict__ c2,
                                              const float* __restrict__ c3,
                                              float* __restrict__ out) {
  // 16 m-rows total (1+3+5+7) x 128 floats = 8 KB
  __shared__ float sc[16 * NFEAT];

  const int sn  = blockIdx.x;
  const int tid = threadIdx.x;

  // Stage all four c-tiles: 512 float4 total, 2 per thread.
  // LDS rows: l0 -> row 0, l1 -> rows 1-3, l2 -> rows 4-8, l3 -> rows 9-15.
  {
    const float4* s0 = (const float4*)(c0 + (size_t)sn * (1 * NFEAT));
    const float4* s1 = (const float4*)(c1 + (size_t)sn * (3 * NFEAT));
    const float4* s2 = (const float4*)(c2 + (size_t)sn * (5 * NFEAT));
    const float4* s3 = (const float4*)(c3 + (size_t)sn * (7 * NFEAT));
    float4* d = (float4*)sc;
#pragma unroll
    for (int rep = 0; rep < 2; ++rep) {
      const int t = tid + rep * 256;
      float4 v;
      if (t < 32)       v = s0[t];
      else if (t < 128) v = s1[t - 32];
      else if (t < 288) v = s2[t - 128];
      else              v = s3[t - 288];
      d[t] = v;
    }
  }
  __syncthreads();

  const int j4 = tid & 31;   // float4 column 0..31  (j = 4*j4 .. 4*j4+3)
  const int i0 = tid >> 5;   // row phase 0..7

  float* obase = out + (size_t)sn * (4 * NFEAT * NFEAT);

  do_l<1>(sc + 0 * NFEAT, kCg[0], obase + 0 * NFEAT * NFEAT, i0, j4);
  do_l<3>(sc + 1 * NFEAT, kCg[1], obase + 1 * NFEAT * NFEAT, i0, j4);
  do_l<5>(sc + 4 * NFEAT, kCg[2], obase + 2 * NFEAT * NFEAT, i0, j4);
  do_l<7>(sc + 9 * NFEAT, kCg[3], obase + 3 * NFEAT * NFEAT, i0, j4);
}

extern "C" void kernel_launch(void* const* d_in, const int* in_sizes, int n_in,
                              void* d_out, int out_size, void* d_ws, size_t ws_size,
                              hipStream_t stream) {
  const float* c0 = (const float*)d_in[0];
  const float* c1 = (const float*)d_in[1];
  const float* c2 = (const float*)d_in[2];
  const float* c3 = (const float*)d_in[3];
  float* out = (float*)d_out;

  // in_sizes are ELEMENT counts: c_l0 is (S, N, 1, 128) f32 -> S*N = elems / 128.
  const int nsn = in_sizes[0] / NFEAT;

  dim3 block(256);
  dim3 grid(nsn);
  ps_all<<<grid, block, 0, stream>>>(c0, c1, c2, c3, out);
}